// Round 3
// baseline (177.009 us; speedup 1.0000x reference)
//
#include <hip/hip_runtime.h>
#include <hip/hip_bf16.h>

typedef unsigned short u16;
typedef __bf16 bf16x8 __attribute__((ext_vector_type(8)));
typedef float f32x4 __attribute__((ext_vector_type(4)));

#define AS1 __attribute__((address_space(1)))
#define AS3 __attribute__((address_space(3)))
#define FENCE asm volatile("" ::: "memory")

__device__ inline void gload_lds16(const void* g, void* l) {
    __builtin_amdgcn_global_load_lds((const AS1 void*)g, (AS3 void*)l, 16, 0, 0);
}

__device__ inline u16 f2bf(float f) {
    __hip_bfloat16 h = __float2bfloat16(f);
    return __builtin_bit_cast(u16, h);
}

// ---------------------------------------------------------------------------
// fp32 -> bf16 convert, 4 elements/thread
// ---------------------------------------------------------------------------
__global__ __launch_bounds__(256)
void cvt_f32_bf16(const float4* __restrict__ in, u16* __restrict__ out, int n4) {
    int i = blockIdx.x * 256 + threadIdx.x;
    if (i >= n4) return;
    float4 v = in[i];
    uint2 pk;
    pk.x = (unsigned)f2bf(v.x) | ((unsigned)f2bf(v.y) << 16);
    pk.y = (unsigned)f2bf(v.z) | ((unsigned)f2bf(v.w) << 16);
    *(uint2*)(out + (long long)i * 4) = pk;
}

// ---------------------------------------------------------------------------
// bf16 transpose within each batch: Vt[b][d][k] = V[b][k][d]
// ---------------------------------------------------------------------------
__global__ __launch_bounds__(256)
void transpose_v(const u16* __restrict__ V, u16* __restrict__ Vt) {
    __shared__ u16 tile[32][33];
    const int b  = blockIdx.z;
    const int d0 = blockIdx.x * 32;
    const int k0 = blockIdx.y * 32;
    const int tx = threadIdx.x & 31;
    const int ty = threadIdx.x >> 5;  // 0..7
    #pragma unroll
    for (int r = ty; r < 32; r += 8)
        tile[r][tx] = V[((long long)b * 1024 + k0 + r) * 1024 + d0 + tx];
    __syncthreads();
    #pragma unroll
    for (int r = ty; r < 32; r += 8)
        Vt[((long long)b * 1024 + d0 + r) * 1024 + k0 + tx] = tile[tx][r];
}

// ---------------------------------------------------------------------------
// 256x256-tile deep-pipelined projection GEMM (bf16, B^T layout, bias, bf16 out)
//   C[z][m][n] = sum_k A[m][k] * W[z][n][k] + bias_z[n]
// 512 threads = 8 waves (2M x 4N), per-wave 128x64 output, BK=32, quad-buffer
// LDS, counted vmcnt(4), XOR slot swizzle, setprio around MFMA.
// K = 1024 -> 32 K-tiles -> NIT = 16 iterations x 2 K-tiles.
// ---------------------------------------------------------------------------
__global__ __launch_bounds__(512, 1)
void gemm256_proj(const u16* __restrict__ A, const u16* __restrict__ W,
                  const float* __restrict__ b0, const float* __restrict__ b1,
                  const float* __restrict__ b2, u16* __restrict__ Out)
{
    constexpr int K = 1024;
    constexpr int NIT = K / 64;   // 2 K-tiles (BK=32) per iteration
    __shared__ u16 sA[4][8192];   // [buf][256 rows x 32 cols]
    __shared__ u16 sB[4][8192];
    const int bz = blockIdx.z;
    const long long col0 = blockIdx.x * 256;
    const long long row0 = blockIdx.y * 256;
    const u16* Ab = A + row0 * K;
    const u16* Bb = W + (long long)bz * (1024LL * 1024) + col0 * K;

    const int t = (int)threadIdx.x, l = t & 63, w = t >> 6;
    const int wr = w >> 2, wc = w & 3;          // wave tile: rows wr*128, cols wc*64
    const int fr = l & 15, fq = l >> 4;

    // staging constants: one 16B granule per thread per half-tile (128 rows x 32 cols)
    const int srow = t >> 2;                     // row within half-tile
    const int ssrc = (t & 3) ^ ((t >> 3) & 3);   // inverse-swizzled 16B slot
    const int gst  = srow * K + ssrc * 8;        // element offset within slab
    const int dsto = w * 512;                    // u16 offset (lane*16B implicit)

    // read constants
    const int sl    = fq ^ ((fr >> 1) & 3);      // swizzled slot for ds_read
    const int aBase = (wr * 128 + fr) * 32 + sl * 8;
    const int bBase = (wc * 64  + fr) * 32 + sl * 8;

    f32x4 acc[8][4];
    #pragma unroll
    for (int m = 0; m < 8; ++m)
        #pragma unroll
        for (int n = 0; n < 4; ++n) acc[m][n] = (f32x4){0.f, 0.f, 0.f, 0.f};

    // prologue: stage kt0 -> buf0, kt1 -> buf1 (A-h0, A-h1, B-h0, B-h1 each)
    #pragma unroll
    for (int kt = 0; kt < 2; ++kt) {
        const u16* as = Ab + kt * 32;
        const u16* bs = Bb + kt * 32;
        gload_lds16(as + gst,           (u16*)sA[kt] + dsto);
        gload_lds16(as + 128 * K + gst, (u16*)sA[kt] + 4096 + dsto);
        gload_lds16(bs + gst,           (u16*)sB[kt] + dsto);
        gload_lds16(bs + 128 * K + gst, (u16*)sB[kt] + 4096 + dsto);
    }
    asm volatile("s_waitcnt vmcnt(4)" ::: "memory");   // kt0 resident
    __builtin_amdgcn_s_barrier();
    FENCE;

    bf16x8 aF[4], bF[4];
    for (int it = 0; it < NIT; ++it) {
        const int c0 = (2 * it) & 3,     c1 = (2 * it + 1) & 3;
        const int n0 = (2 * it + 2) & 3, n1 = (2 * it + 3) & 3;
        const bool st = (it < NIT - 1);
        const u16* as0 = Ab + (2 * it + 2) * 32;
        const u16* bs0 = Bb + (2 * it + 2) * 32;
        const u16* as1 = Ab + (2 * it + 3) * 32;
        const u16* bs1 = Bb + (2 * it + 3) * 32;

        // ---- phase 0: kt-even, m0-3 ----
        {
            const u16* bufA = sA[c0]; const u16* bufB = sB[c0];
            #pragma unroll
            for (int n = 0; n < 4; ++n) bF[n] = *(const bf16x8*)(bufB + bBase + n * 512);
            #pragma unroll
            for (int i = 0; i < 4; ++i) aF[i] = *(const bf16x8*)(bufA + aBase + i * 512);
            if (st) {
                gload_lds16(as0 + gst,           (u16*)sA[n0] + dsto);
                gload_lds16(as0 + 128 * K + gst, (u16*)sA[n0] + 4096 + dsto);
            }
            FENCE;
            __builtin_amdgcn_s_barrier();
            asm volatile("s_waitcnt lgkmcnt(0)" ::: "memory");
            __builtin_amdgcn_sched_barrier(0);
            __builtin_amdgcn_s_setprio(1);
            #pragma unroll
            for (int i = 0; i < 4; ++i)
                #pragma unroll
                for (int n = 0; n < 4; ++n)
                    acc[i][n] = __builtin_amdgcn_mfma_f32_16x16x32_bf16(aF[i], bF[n], acc[i][n], 0, 0, 0);
            __builtin_amdgcn_s_setprio(0);
            FENCE;
            __builtin_amdgcn_s_barrier();
        }
        // ---- phase 1: kt-even, m4-7; boundary wait ----
        {
            const u16* bufA = sA[c0];
            #pragma unroll
            for (int i = 0; i < 4; ++i) aF[i] = *(const bf16x8*)(bufA + aBase + (4 + i) * 512);
            if (st) {
                gload_lds16(bs0 + gst,           (u16*)sB[n0] + dsto);
                gload_lds16(bs0 + 128 * K + gst, (u16*)sB[n0] + 4096 + dsto);
            }
            FENCE;
            __builtin_amdgcn_s_barrier();
            asm volatile("s_waitcnt lgkmcnt(0)" ::: "memory");
            __builtin_amdgcn_sched_barrier(0);
            __builtin_amdgcn_s_setprio(1);
            #pragma unroll
            for (int i = 0; i < 4; ++i)
                #pragma unroll
                for (int n = 0; n < 4; ++n)
                    acc[4 + i][n] = __builtin_amdgcn_mfma_f32_16x16x32_bf16(aF[i], bF[n], acc[4 + i][n], 0, 0, 0);
            __builtin_amdgcn_s_setprio(0);
            if (st) asm volatile("s_waitcnt vmcnt(4)" ::: "memory");  // kt-odd resident
            else    asm volatile("s_waitcnt vmcnt(0)" ::: "memory");
            FENCE;
            __builtin_amdgcn_s_barrier();
        }
        // ---- phase 2: kt-odd, m0-3 ----
        {
            const u16* bufA = sA[c1]; const u16* bufB = sB[c1];
            #pragma unroll
            for (int n = 0; n < 4; ++n) bF[n] = *(const bf16x8*)(bufB + bBase + n * 512);
            #pragma unroll
            for (int i = 0; i < 4; ++i) aF[i] = *(const bf16x8*)(bufA + aBase + i * 512);
            if (st) {
                gload_lds16(as1 + gst,           (u16*)sA[n1] + dsto);
                gload_lds16(as1 + 128 * K + gst, (u16*)sA[n1] + 4096 + dsto);
            }
            FENCE;
            __builtin_amdgcn_s_barrier();
            asm volatile("s_waitcnt lgkmcnt(0)" ::: "memory");
            __builtin_amdgcn_sched_barrier(0);
            __builtin_amdgcn_s_setprio(1);
            #pragma unroll
            for (int i = 0; i < 4; ++i)
                #pragma unroll
                for (int n = 0; n < 4; ++n)
                    acc[i][n] = __builtin_amdgcn_mfma_f32_16x16x32_bf16(aF[i], bF[n], acc[i][n], 0, 0, 0);
            __builtin_amdgcn_s_setprio(0);
            FENCE;
            __builtin_amdgcn_s_barrier();
        }
        // ---- phase 3: kt-odd, m4-7; boundary wait ----
        {
            const u16* bufA = sA[c1];
            #pragma unroll
            for (int i = 0; i < 4; ++i) aF[i] = *(const bf16x8*)(bufA + aBase + (4 + i) * 512);
            if (st) {
                gload_lds16(bs1 + gst,           (u16*)sB[n1] + dsto);
                gload_lds16(bs1 + 128 * K + gst, (u16*)sB[n1] + 4096 + dsto);
            }
            FENCE;
            __builtin_amdgcn_s_barrier();
            asm volatile("s_waitcnt lgkmcnt(0)" ::: "memory");
            __builtin_amdgcn_sched_barrier(0);
            __builtin_amdgcn_s_setprio(1);
            #pragma unroll
            for (int i = 0; i < 4; ++i)
                #pragma unroll
                for (int n = 0; n < 4; ++n)
                    acc[4 + i][n] = __builtin_amdgcn_mfma_f32_16x16x32_bf16(aF[i], bF[n], acc[4 + i][n], 0, 0, 0);
            __builtin_amdgcn_s_setprio(0);
            if (st) asm volatile("s_waitcnt vmcnt(4)" ::: "memory");  // next kt-even resident
            FENCE;
            __builtin_amdgcn_s_barrier();
        }
    }

    // epilogue: bias + bf16 store
    const float* bp = (bz == 0) ? b0 : ((bz == 1) ? b1 : b2);
    u16* C = Out + (long long)bz * (8192LL * 1024);
    #pragma unroll
    for (int n = 0; n < 4; ++n) {
        const long long cn = col0 + wc * 64 + n * 16 + fr;
        const float bv = bp[cn];
        #pragma unroll
        for (int m = 0; m < 8; ++m) {
            const long long cm = row0 + wr * 128 + m * 16 + fq * 4;
            #pragma unroll
            for (int j = 0; j < 4; ++j)
                C[(cm + j) * 1024 + cn] = f2bf(acc[m][n][j] + bv);
        }
    }
}

// ---------------------------------------------------------------------------
// m97-structure bf16 GEMM, B^T layout: C[m][n] = sum_k A[m][k] * Bt[n][k]
// MODE 1: scores (f32 out, * scale, skip blocks strictly above diagonal)
// MODE 2: pv    (f32 out, K-loop limited to row0+BM  — causal)
// ---------------------------------------------------------------------------
template<int MODE>
__global__ __launch_bounds__(256)
void gemm_bt(const u16* __restrict__ A, long long strideA,
             const u16* __restrict__ Bt, long long strideB,
             void* __restrict__ Cv, long long strideC,
             int M, int N, int K, float scale)
{
    constexpr int BM = 128, BN = 128, BK = 32;
    __shared__ __align__(16) u16 shA[BM * BK];
    __shared__ __align__(16) u16 shB[BN * BK];
    const int bz   = blockIdx.z;
    const int row0 = blockIdx.y * BM;
    const int col0 = blockIdx.x * BN;
    if (MODE == 1 && col0 > row0) return;  // fully-masked causal block
    const u16* Ab = A  + (long long)bz * strideA;
    const u16* Bb = Bt + (long long)bz * strideB;
    int kEnd = K;
    if (MODE == 2) kEnd = (row0 + BM < K) ? (row0 + BM) : K;

    const int t  = (int)threadIdx.x;
    const int l  = t & 63;
    const int w  = t >> 6;
    const int wr = w >> 1, wc = w & 1;
    const int fr = l & 15, fq = l >> 4;

    f32x4 acc[4][4];
    const f32x4 zero = {0.f, 0.f, 0.f, 0.f};
    #pragma unroll
    for (int m = 0; m < 4; ++m)
        #pragma unroll
        for (int n = 0; n < 4; ++n)
            acc[m][n] = zero;

    for (int kk = 0; kk < kEnd; kk += BK) {
        if (kk) __syncthreads();
        #pragma unroll
        for (int r = 0; r < 2; ++r) {
            const int s    = t + r * 256;       // 16B slot index
            const int rrow = s >> 2;            // tile row (of 128)
            const int rcol = (s & 3) << 3;      // bf16 column offset
            gload_lds16(Ab + (long long)(row0 + rrow) * K + kk + rcol, (void*)(shA + s * 8));
            gload_lds16(Bb + (long long)(col0 + rrow) * K + kk + rcol, (void*)(shB + s * 8));
        }
        __syncthreads();
        bf16x8 aF[4], bF[4];
        #pragma unroll
        for (int m = 0; m < 4; ++m)
            aF[m] = *(const bf16x8*)(shA + (wr * 64 + m * 16 + fr) * BK + fq * 8);
        #pragma unroll
        for (int n = 0; n < 4; ++n)
            bF[n] = *(const bf16x8*)(shB + (wc * 64 + n * 16 + fr) * BK + fq * 8);
        #pragma unroll
        for (int m = 0; m < 4; ++m)
            #pragma unroll
            for (int n = 0; n < 4; ++n)
                acc[m][n] = __builtin_amdgcn_mfma_f32_16x16x32_bf16(aF[m], bF[n], acc[m][n], 0, 0, 0);
    }

    float* C = (float*)Cv + (long long)bz * strideC;
    #pragma unroll
    for (int n = 0; n < 4; ++n) {
        const int cn = col0 + wc * 64 + n * 16 + fr;
        #pragma unroll
        for (int m = 0; m < 4; ++m) {
            const int cm = row0 + wr * 64 + m * 16 + fq * 4;
            #pragma unroll
            for (int j = 0; j < 4; ++j)
                C[(long long)(cm + j) * N + cn] = acc[m][n][j] * scale;
        }
    }
}

// ---------------------------------------------------------------------------
// causal row softmax: P[row][j] = softmax(S[row][0..q]) as bf16, 0 for j>q
// ---------------------------------------------------------------------------
__global__ __launch_bounds__(256)
void softmax_causal(const float* __restrict__ S, u16* __restrict__ P) {
    __shared__ float redM[4], redS[4];
    const int row = blockIdx.x;
    const int q   = row & 1023;
    const int t   = (int)threadIdx.x;
    const int l   = t & 63, w = t >> 6;
    const float4* srow = (const float4*)(S + (long long)row * 1024);
    float4 v = srow[t];
    const int j0 = t * 4;
    float x0 = (j0 + 0 <= q) ? v.x : -1e30f;
    float x1 = (j0 + 1 <= q) ? v.y : -1e30f;
    float x2 = (j0 + 2 <= q) ? v.z : -1e30f;
    float x3 = (j0 + 3 <= q) ? v.w : -1e30f;
    float m = fmaxf(fmaxf(x0, x1), fmaxf(x2, x3));
    #pragma unroll
    for (int o = 32; o > 0; o >>= 1) m = fmaxf(m, __shfl_xor(m, o, 64));
    if (l == 0) redM[w] = m;
    __syncthreads();
    m = fmaxf(fmaxf(redM[0], redM[1]), fmaxf(redM[2], redM[3]));
    float e0 = __expf(x0 - m);
    float e1 = __expf(x1 - m);
    float e2 = __expf(x2 - m);
    float e3 = __expf(x3 - m);
    float s = e0 + e1 + e2 + e3;
    #pragma unroll
    for (int o = 32; o > 0; o >>= 1) s += __shfl_xor(s, o, 64);
    if (l == 0) redS[w] = s;
    __syncthreads();
    s = redS[0] + redS[1] + redS[2] + redS[3];
    const float inv = 1.0f / s;
    uint2 pk;
    pk.x = (unsigned)f2bf(e0 * inv) | ((unsigned)f2bf(e1 * inv) << 16);
    pk.y = (unsigned)f2bf(e2 * inv) | ((unsigned)f2bf(e3 * inv) << 16);
    *(uint2*)(P + (long long)row * 1024 + j0) = pk;
}

// ---------------------------------------------------------------------------
extern "C" void kernel_launch(void* const* d_in, const int* in_sizes, int n_in,
                              void* d_out, int out_size, void* d_ws, size_t ws_size,
                              hipStream_t stream) {
    const float* x  = (const float*)d_in[0];
    const float* Wq = (const float*)d_in[1];
    const float* bq = (const float*)d_in[2];
    const float* Wk = (const float*)d_in[3];
    const float* bk = (const float*)d_in[4];
    const float* Wv = (const float*)d_in[5];
    const float* bv = (const float*)d_in[6];
    float* out = (float*)d_out;
    char* ws = (char*)d_ws;

    // workspace layout (134 MB total)
    u16*   xb  = (u16*)(ws + 0);                      // 16 MB  [8192][1024] bf16
    u16*   Wb  = (u16*)(ws + ((size_t)16 << 20));     //  6 MB  [3][1024][1024] bf16
    u16*   QKV = (u16*)(ws + ((size_t)22 << 20));     // 48 MB  [3][8192][1024] bf16
    u16*   Vt  = (u16*)(ws + ((size_t)70 << 20));     // 16 MB  [8][1024][1024] bf16 (d,k)
    float* SC  = (float*)(ws + ((size_t)86 << 20));   // 32 MB  [8][1024][1024] f32
    u16*   P   = (u16*)(ws + ((size_t)118 << 20));    // 16 MB  [8][1024][1024] bf16

    // 1) convert to bf16
    cvt_f32_bf16<<<8192, 256, 0, stream>>>((const float4*)x, xb, 8388608 / 4);
    cvt_f32_bf16<<<1024, 256, 0, stream>>>((const float4*)Wq, Wb, 1048576 / 4);
    cvt_f32_bf16<<<1024, 256, 0, stream>>>((const float4*)Wk, Wb + 1048576, 1048576 / 4);
    cvt_f32_bf16<<<1024, 256, 0, stream>>>((const float4*)Wv, Wb + 2097152, 1048576 / 4);

    // 2) Q,K,V projections — 256² deep-pipelined kernel (grid.z selects weight/bias)
    gemm256_proj<<<dim3(4, 32, 3), 512, 0, stream>>>(xb, Wb, bq, bk, bv, QKV);

    // 3) V transpose for PV gemm
    transpose_v<<<dim3(32, 32, 8), 256, 0, stream>>>(QKV + 2 * 8388608LL, Vt);

    // 4) scores = Q K^T / 32 (causal block skip)
    gemm_bt<1><<<dim3(8, 8, 8), 256, 0, stream>>>(QKV, 1048576LL, QKV + 8388608LL, 1048576LL,
                                                  SC, 1048576LL, 1024, 1024, 1024, 0.03125f);

    // 5) causal softmax -> P (bf16)
    softmax_causal<<<8192, 256, 0, stream>>>(SC, P);

    // 6) O = P V   (K-loop causally limited)
    gemm_bt<2><<<dim3(8, 8, 8), 256, 0, stream>>>(P, 1048576LL, Vt, 1048576LL, out, 1048576LL,
                                                  1024, 1024, 1024, 1.0f);
}

// Round 4
// 124.800 us; speedup vs baseline: 1.4183x; 1.4183x over previous
//
#include <hip/hip_runtime.h>
#include <hip/hip_bf16.h>

typedef unsigned short u16;
typedef __bf16 bf16x8 __attribute__((ext_vector_type(8)));
typedef float f32x4 __attribute__((ext_vector_type(4)));

#define AS1 __attribute__((address_space(1)))
#define AS3 __attribute__((address_space(3)))

__device__ inline void gload_lds16(const void* g, void* l) {
    __builtin_amdgcn_global_load_lds((const AS1 void*)g, (AS3 void*)l, 16, 0, 0);
}

__device__ inline u16 f2bf(float f) {
    __hip_bfloat16 h = __float2bfloat16(f);
    return __builtin_bit_cast(u16, h);
}

// ---------------------------------------------------------------------------
// fused fp32 -> bf16 convert for x, Wq, Wk, Wv (one launch)
// segment boundaries in float4 units: x 2097152, then 3x 262144
// ---------------------------------------------------------------------------
__global__ __launch_bounds__(256)
void cvt_all(const float4* __restrict__ x,  const float4* __restrict__ wq,
             const float4* __restrict__ wk, const float4* __restrict__ wv,
             u16* __restrict__ xb, u16* __restrict__ Wb) {
    int i = blockIdx.x * 256 + threadIdx.x;
    const float4* src; u16* dst; int off;
    if (i < 2097152)      { src = x;  dst = xb;            off = i; }
    else if (i < 2359296) { src = wq; dst = Wb;            off = i - 2097152; }
    else if (i < 2621440) { src = wk; dst = Wb + 1048576;  off = i - 2359296; }
    else                  { src = wv; dst = Wb + 2097152;  off = i - 2621440; }
    float4 v = src[off];
    uint2 pk;
    pk.x = (unsigned)f2bf(v.x) | ((unsigned)f2bf(v.y) << 16);
    pk.y = (unsigned)f2bf(v.z) | ((unsigned)f2bf(v.w) << 16);
    *(uint2*)(dst + (long long)off * 4) = pk;
}

// ---------------------------------------------------------------------------
// bf16 transpose within each batch: Vt[b][d][k] = V[b][k][d]
// ---------------------------------------------------------------------------
__global__ __launch_bounds__(256)
void transpose_v(const u16* __restrict__ V, u16* __restrict__ Vt) {
    __shared__ u16 tile[32][33];
    const int b  = blockIdx.z;
    const int d0 = blockIdx.x * 32;
    const int k0 = blockIdx.y * 32;
    const int tx = threadIdx.x & 31;
    const int ty = threadIdx.x >> 5;
    #pragma unroll
    for (int r = ty; r < 32; r += 8)
        tile[r][tx] = V[((long long)b * 1024 + k0 + r) * 1024 + d0 + tx];
    __syncthreads();
    #pragma unroll
    for (int r = ty; r < 32; r += 8)
        Vt[((long long)b * 1024 + d0 + r) * 1024 + k0 + tx] = tile[tx][r];
}

// ---------------------------------------------------------------------------
// 128x128-tile bf16 GEMM (B^T layout), BK=64, granule-XOR LDS swizzle,
// XCD-aware block remap.  C[m][n] = sum_k A[m][k] * Bt[n][k]
// MODE 0: proj   (bias by z, bf16 out; remap: XCD = A-row slab)
// MODE 1: scores (f32 out *scale, causal block skip; XCD = batch)
// MODE 2: pv     (f32 out, K-loop limited to row0+128; XCD = batch)
// LDS layout: slot s (16B granules), row = s>>3, holds global granule
// (s&7) ^ (row&7) of that row.  Reader XORs the same -> involution (rule #21).
// ---------------------------------------------------------------------------
template<int MODE>
__global__ __launch_bounds__(256)
void gemm_bt(const u16* __restrict__ A, long long strideA,
             const u16* __restrict__ Bt, long long strideB,
             void* __restrict__ Cv, long long strideC,
             const float* __restrict__ bias0, const float* __restrict__ bias1,
             const float* __restrict__ bias2,
             int N, int K, float scale)
{
    constexpr int BK = 64;
    __shared__ __align__(16) u16 shA[128 * BK];   // 16 KB
    __shared__ __align__(16) u16 shB[128 * BK];   // 16 KB
    int bz, row0, col0;
    if (MODE == 0) {
        // grid (8,64,3); XCD = blockIdx.x owns rows [x*1024, x*1024+1024)
        bz   = blockIdx.z;
        row0 = (blockIdx.x * 8 + (blockIdx.y & 7)) * 128;
        col0 = (int)(blockIdx.y >> 3) * 128;
    } else {
        // grid (8,8,8); XCD = blockIdx.x = batch
        bz   = blockIdx.x;
        row0 = blockIdx.y * 128;
        col0 = blockIdx.z * 128;
    }
    if (MODE == 1 && col0 > row0) return;   // fully-masked causal block
    const u16* Ab = A  + (long long)bz * strideA + (long long)row0 * K;
    const u16* Bb = Bt + (long long)bz * strideB + (long long)col0 * K;
    int kEnd = K;
    if (MODE == 2) kEnd = (row0 + 128 < K) ? (row0 + 128) : K;

    const int t  = (int)threadIdx.x;
    const int l  = t & 63;
    const int w  = t >> 6;
    const int wr = w >> 1, wc = w & 1;
    const int fr = l & 15, fq = l >> 4;

    f32x4 acc[4][4];
    #pragma unroll
    for (int m = 0; m < 4; ++m)
        #pragma unroll
        for (int n = 0; n < 4; ++n)
            acc[m][n] = (f32x4){0.f, 0.f, 0.f, 0.f};

    // precomputed swizzled read offsets (u16 units)
    int aOff[2][4], bOff[2][4];
    #pragma unroll
    for (int kh = 0; kh < 2; ++kh) {
        const int g = ((kh * 4 + fq) ^ (fr & 7)) * 8;
        #pragma unroll
        for (int m = 0; m < 4; ++m) aOff[kh][m] = (wr * 64 + m * 16 + fr) * 64 + g;
        #pragma unroll
        for (int n = 0; n < 4; ++n) bOff[kh][n] = (wc * 64 + n * 16 + fr) * 64 + g;
    }

    for (int kk = 0; kk < kEnd; kk += BK) {
        if (kk) __syncthreads();
        #pragma unroll
        for (int r = 0; r < 4; ++r) {
            const int s  = t + r * 256;          // 16B slot, 0..1023
            const int rw = s >> 3;               // tile row
            const int g  = (s & 7) ^ (rw & 7);   // inverse-swizzled source granule
            gload_lds16(Ab + (long long)rw * K + kk + g * 8, (void*)(shA + s * 8));
            gload_lds16(Bb + (long long)rw * K + kk + g * 8, (void*)(shB + s * 8));
        }
        __syncthreads();
        bf16x8 aF[2][4], bF[2][4];
        #pragma unroll
        for (int kh = 0; kh < 2; ++kh) {
            #pragma unroll
            for (int m = 0; m < 4; ++m) aF[kh][m] = *(const bf16x8*)(shA + aOff[kh][m]);
            #pragma unroll
            for (int n = 0; n < 4; ++n) bF[kh][n] = *(const bf16x8*)(shB + bOff[kh][n]);
        }
        #pragma unroll
        for (int kh = 0; kh < 2; ++kh)
            #pragma unroll
            for (int m = 0; m < 4; ++m)
                #pragma unroll
                for (int n = 0; n < 4; ++n)
                    acc[m][n] = __builtin_amdgcn_mfma_f32_16x16x32_bf16(aF[kh][m], bF[kh][n], acc[m][n], 0, 0, 0);
    }

    if (MODE == 0) {
        const float* bp = (bz == 0) ? bias0 : ((bz == 1) ? bias1 : bias2);
        u16* C = (u16*)Cv + (long long)bz * strideC;
        #pragma unroll
        for (int n = 0; n < 4; ++n) {
            const int cn = col0 + wc * 64 + n * 16 + fr;
            const float bv = bp[cn];
            #pragma unroll
            for (int m = 0; m < 4; ++m) {
                const int cm = row0 + wr * 64 + m * 16 + fq * 4;
                #pragma unroll
                for (int j = 0; j < 4; ++j)
                    C[(long long)(cm + j) * N + cn] = f2bf(acc[m][n][j] + bv);
            }
        }
    } else {
        float* C = (float*)Cv + (long long)bz * strideC;
        #pragma unroll
        for (int n = 0; n < 4; ++n) {
            const int cn = col0 + wc * 64 + n * 16 + fr;
            #pragma unroll
            for (int m = 0; m < 4; ++m) {
                const int cm = row0 + wr * 64 + m * 16 + fq * 4;
                #pragma unroll
                for (int j = 0; j < 4; ++j)
                    C[(long long)(cm + j) * N + cn] = acc[m][n][j] * scale;
            }
        }
    }
}

// ---------------------------------------------------------------------------
// causal row softmax: P[row][j] = softmax(S[row][0..q]) bf16, 0 for j>q
// masked float4s are never loaded (halves the read on average)
// ---------------------------------------------------------------------------
__global__ __launch_bounds__(256)
void softmax_causal(const float* __restrict__ S, u16* __restrict__ P) {
    __shared__ float redM[4], redS[4];
    const int row = blockIdx.x;
    const int q   = row & 1023;
    const int t   = (int)threadIdx.x;
    const int l   = t & 63, w = t >> 6;
    const int j0  = t * 4;
    float x0 = -1e30f, x1 = -1e30f, x2 = -1e30f, x3 = -1e30f;
    if (j0 <= q) {
        float4 v = ((const float4*)(S + (long long)row * 1024))[t];
        x0 = v.x;
        x1 = (j0 + 1 <= q) ? v.y : -1e30f;
        x2 = (j0 + 2 <= q) ? v.z : -1e30f;
        x3 = (j0 + 3 <= q) ? v.w : -1e30f;
    }
    float m = fmaxf(fmaxf(x0, x1), fmaxf(x2, x3));
    #pragma unroll
    for (int o = 32; o > 0; o >>= 1) m = fmaxf(m, __shfl_xor(m, o, 64));
    if (l == 0) redM[w] = m;
    __syncthreads();
    m = fmaxf(fmaxf(redM[0], redM[1]), fmaxf(redM[2], redM[3]));
    float e0 = __expf(x0 - m);
    float e1 = __expf(x1 - m);
    float e2 = __expf(x2 - m);
    float e3 = __expf(x3 - m);
    float s = e0 + e1 + e2 + e3;
    #pragma unroll
    for (int o = 32; o > 0; o >>= 1) s += __shfl_xor(s, o, 64);
    if (l == 0) redS[w] = s;
    __syncthreads();
    s = redS[0] + redS[1] + redS[2] + redS[3];
    const float inv = 1.0f / s;
    uint2 pk;
    pk.x = (unsigned)f2bf(e0 * inv) | ((unsigned)f2bf(e1 * inv) << 16);
    pk.y = (unsigned)f2bf(e2 * inv) | ((unsigned)f2bf(e3 * inv) << 16);
    *(uint2*)(P + (long long)row * 1024 + j0) = pk;
}

// ---------------------------------------------------------------------------
extern "C" void kernel_launch(void* const* d_in, const int* in_sizes, int n_in,
                              void* d_out, int out_size, void* d_ws, size_t ws_size,
                              hipStream_t stream) {
    const float* x  = (const float*)d_in[0];
    const float* Wq = (const float*)d_in[1];
    const float* bq = (const float*)d_in[2];
    const float* Wk = (const float*)d_in[3];
    const float* bk = (const float*)d_in[4];
    const float* Wv = (const float*)d_in[5];
    const float* bv = (const float*)d_in[6];
    float* out = (float*)d_out;
    char* ws = (char*)d_ws;

    // workspace layout (134 MB total)
    u16*   xb  = (u16*)(ws + 0);                      // 16 MB  [8192][1024] bf16
    u16*   Wb  = (u16*)(ws + ((size_t)16 << 20));     //  6 MB  [3][1024][1024] bf16
    u16*   QKV = (u16*)(ws + ((size_t)22 << 20));     // 48 MB  [3][8192][1024] bf16
    u16*   Vt  = (u16*)(ws + ((size_t)70 << 20));     // 16 MB  [8][1024][1024] bf16 (d,k)
    float* SC  = (float*)(ws + ((size_t)86 << 20));   // 32 MB  [8][1024][1024] f32
    u16*   P   = (u16*)(ws + ((size_t)118 << 20));    // 16 MB  [8][1024][1024] bf16

    // 1) convert everything to bf16 (single launch)
    cvt_all<<<11264, 256, 0, stream>>>((const float4*)x, (const float4*)Wq,
                                       (const float4*)Wk, (const float4*)Wv, xb, Wb);

    // 2) Q,K,V projections
    gemm_bt<0><<<dim3(8, 64, 3), 256, 0, stream>>>(xb, 0LL, Wb, 1048576LL, QKV, 8388608LL,
                                                   bq, bk, bv, 1024, 1024, 1.0f);

    // 3) V transpose for PV gemm
    transpose_v<<<dim3(32, 32, 8), 256, 0, stream>>>(QKV + 2 * 8388608LL, Vt);

    // 4) scores = Q K^T / 32 (causal block skip; blockIdx.x = batch)
    gemm_bt<1><<<dim3(8, 8, 8), 256, 0, stream>>>(QKV, 1048576LL, QKV + 8388608LL, 1048576LL,
                                                  SC, 1048576LL, nullptr, nullptr, nullptr,
                                                  1024, 1024, 0.03125f);

    // 5) causal softmax -> P (bf16)
    softmax_causal<<<8192, 256, 0, stream>>>(SC, P);

    // 6) O = P V   (K-loop causally limited; blockIdx.x = batch)
    gemm_bt<2><<<dim3(8, 8, 8), 256, 0, stream>>>(P, 1048576LL, Vt, 1048576LL, out, 1048576LL,
                                                  nullptr, nullptr, nullptr,
                                                  1024, 1024, 1.0f);
}